// Round 4
// baseline (381.699 us; speedup 1.0000x reference)
//
#include <hip/hip_runtime.h>
#include <stdint.h>

#define BATCH 256
#define M 512
#define N 512
#define K 128

typedef int int4v __attribute__((ext_vector_type(4)));
typedef float float4v __attribute__((ext_vector_type(4)));

// One block = one 128x128 output tile of one batch. Grid 4x4x256 = 4096
// blocks, 256 threads (4 waves, 2x2 wave grid, 64x64 per wave).
// LDS 32 KB -> ~3 blocks/CU resident: staging of one block overlaps
// compute/stores of another (R3's 1-block/CU phase-serial design was the
// 361us bottleneck). Inputs arrive widened to int32; we pack to int8 in
// XOR-swizzled LDS (layout verified in R3). Input tile re-reads (4x each)
// are served by L2/L3 (entire input set 134 MB < 256 MB L3).
__global__ __launch_bounds__(256, 3) void bmm_s8s8_f32_kernel(
    const int* __restrict__ A32,       // [BATCH, M, K] int32 in [-128,127]
    const int* __restrict__ B32,       // [BATCH, N, K] int32
    const float* __restrict__ alpha_p, // scalar
    float* __restrict__ O)             // [BATCH, M, N] fp32
{
    __shared__ int8_t As[128 * 128]; // 16 KB
    __shared__ int8_t Bs[128 * 128]; // 16 KB

    const int tid = threadIdx.x;
    const int bat = blockIdx.z;
    const int mt0 = blockIdx.y * 128;
    const int nt0 = blockIdx.x * 128;

    const int* Ag = A32 + ((size_t)bat * M + mt0) * K;
    const int* Bg = B32 + ((size_t)bat * N + nt0) * K;

    // Stage+pack: 4096 four-int32 groups per matrix; lane loads 16B (4 int32),
    // packs low bytes -> one dword, writes swizzled LDS:
    //   byte addr = row*128 + ((d>>2) ^ (row&7))*16 + (d&3)*4
    // Wave covers 2 rows x 32 dwords: bijective on banks per row -> 2
    // lanes/bank = free (m136). unroll 4 caps in-flight loads (VGPR budget).
#pragma unroll 4
    for (int i = 0; i < 16; ++i) {
        const int g   = i * 256 + tid; // group 0..4095
        const int row = g >> 5;        // 32 groups per row
        const int d   = g & 31;        // dword slot in packed LDS row
        const int loff = row * 128 + (((d >> 2) ^ (row & 7)) << 4) + (d & 3) * 4;

        int4v wa = *(const int4v*)(Ag + (size_t)g * 4);
        int4v wb = *(const int4v*)(Bg + (size_t)g * 4);
        const int pa = (wa.x & 0xff) | ((wa.y & 0xff) << 8) |
                       ((wa.z & 0xff) << 16) | (wa.w << 24);
        const int pb = (wb.x & 0xff) | ((wb.y & 0xff) << 8) |
                       ((wb.z & 0xff) << 16) | (wb.w << 24);
        *(int*)(As + loff) = pa;
        *(int*)(Bs + loff) = pb;
    }
    __syncthreads();

    const int lane = tid & 63;
    const int wave = tid >> 6;
    const int wm   = (wave >> 1) * 64;
    const int wn   = (wave & 1) * 64;
    const int l15  = lane & 15;
    const int quad = lane >> 4;

    // Fragments: lane holds operand row (l15) x 16B k-chunk (quad); the
    // slot->k bijection cancels between the two operands (identical layouts).
    int4v af[2][4], bf[2][4];
#pragma unroll
    for (int ks = 0; ks < 2; ++ks)
#pragma unroll
        for (int i = 0; i < 4; ++i) {
            const int ra = wm + i * 16 + l15;
            const int rb = wn + i * 16 + l15;
            const int kca = (ks * 4 + quad) ^ (ra & 7);
            const int kcb = (ks * 4 + quad) ^ (rb & 7);
            af[ks][i] = *(const int4v*)(As + ra * 128 + kca * 16);
            bf[ks][i] = *(const int4v*)(Bs + rb * 128 + kcb * 16);
        }

    int4v acc[4][4];
#pragma unroll
    for (int i = 0; i < 4; ++i)
#pragma unroll
        for (int j = 0; j < 4; ++j)
            acc[i][j] = (int4v){0, 0, 0, 0};

    // OPERAND SWAP: first operand indexes C/D rows (proven by R3's passing
    // epilogue with mfma(af,bf) -> row=m). With mfma(bf,af):
    //   C/D col = lane&15 = m-index, row = quad*4+reg = n-index
    // -> each lane's 4 regs are 4 CONSECUTIVE n -> float4 stores.
#pragma unroll
    for (int ks = 0; ks < 2; ++ks)
#pragma unroll
        for (int i = 0; i < 4; ++i)
#pragma unroll
            for (int j = 0; j < 4; ++j)
                acc[i][j] = __builtin_amdgcn_mfma_i32_16x16x64_i8(
                    bf[ks][j], af[ks][i], acc[i][j], 0, 0, 0);

    // Epilogue: lane writes O[bat][mt0+wm+i*16+l15][nt0+wn+j*16+quad*4 .. +3]
    const float alpha = *alpha_p;
    float* Ob = O + ((size_t)bat * M + mt0 + wm + l15) * N + nt0 + wn + quad * 4;
#pragma unroll
    for (int i = 0; i < 4; ++i) {
        float* rowp = Ob + (size_t)(i * 16) * N;
#pragma unroll
        for (int j = 0; j < 4; ++j) {
            float4v v;
            v.x = alpha * (float)acc[i][j][0];
            v.y = alpha * (float)acc[i][j][1];
            v.z = alpha * (float)acc[i][j][2];
            v.w = alpha * (float)acc[i][j][3];
            *(float4v*)(rowp + j * 16) = v;
        }
    }
}

extern "C" void kernel_launch(void* const* d_in, const int* in_sizes, int n_in,
                              void* d_out, int out_size, void* d_ws, size_t ws_size,
                              hipStream_t stream) {
    const int*   a     = (const int*)d_in[0];
    const int*   b     = (const int*)d_in[1];
    const float* alpha = (const float*)d_in[2];
    float*       out   = (float*)d_out;

    dim3 grid(N / 128, M / 128, BATCH);
    dim3 block(256);
    bmm_s8s8_f32_kernel<<<grid, block, 0, stream>>>(a, b, alpha, out);
}